// Round 7
// baseline (1462.601 us; speedup 1.0000x reference)
//
#include <hip/hip_runtime.h>
#include <hip/hip_bf16.h>

// SparseDynamicConv3d: out[n,o] = sum_k sum_c feat[idx[k,n],c] * W[k,c,o]
// Round 7: rulebook formulation. Voxel occupancy 4.8% => avg 2.24 of 27
// offsets valid; dense-k iteration wastes ~92% of gathers/FLOPs.
//   1. memset counters
//   2. mega kernel: [featb fp32->bf16 | wtb frag repack | compaction of valid
//      (n,gi) pairs per offset (k!=13) | center GEMM out = feat @ W13 ]
//   3. 1-block tile-descriptor builder (prefix over 26 counts)
//   4. persistent scatter-GEMM: 32-pair tiles, B direct from L2-resident wtb,
//      fp32 atomicAdd epilogue onto out.
// MFMA layouts identical to validated r6 (32x32x16 bf16, K=48 exact).

#define NVOX       100000
#define INC        48
#define INC_MAX    64
#define OUTC       64
#define OUTC_MAX   96
#define KOFF       27
#define KCENTER    13
#define FEAT_ROW   64                        // bf16 row padded to 128 B
#define WTB_K      3072                      // shorts per k (48x64 frag-packed)

// ---- workspace layout (bytes) ----
#define FEATB_OFF  0
#define FEATB_BYTES ((size_t)(NVOX + 1) * FEAT_ROW * 2)          // 12,800,128
#define WTB_OFF    (FEATB_OFF + FEATB_BYTES)
#define WTB_BYTES  ((size_t)KOFF * WTB_K * 2)                    // 165,888
#define PAIRS_OFF  (WTB_OFF + WTB_BYTES)
#define PAIRS_BYTES ((size_t)26 * NVOX * 8)                      // 20,800,000
#define DESC_OFF   (PAIRS_OFF + PAIRS_BYTES)
#define DESC_BYTES ((size_t)26 * 3125 * 8)                       // 650,000
#define CNT_OFF    (DESC_OFF + DESC_BYTES)
#define CNT_BYTES  128                                           // 26 cnt + ntiles
#define WS_NEED    (CNT_OFF + CNT_BYTES)

// ---- mega-kernel block ranges ----
#define FEAT_THREADS ((NVOX + 1) * 8)
#define R0_BLKS    ((FEAT_THREADS + 255) / 256)    // 3126 : featb convert
#define R1_BLKS    (KOFF * WTB_K / 256)            // 324  : wtb repack
#define R2_BLKS    ((26 * NVOX + 255) / 256)       // 10157: compaction
#define R3_BLKS    782                             // center GEMM (3125 waves)
#define MEGA_BLKS  (R0_BLKS + R1_BLKS + R2_BLKS + R3_BLKS)

#define SCAT_BLKS  1024

typedef __attribute__((ext_vector_type(8)))  short short8;
typedef __attribute__((ext_vector_type(4)))  float floatx4;
typedef __attribute__((ext_vector_type(16))) float floatx16;

__device__ __forceinline__ short f2bf(float f) {
    union { __hip_bfloat16 h; short s; } u;
    u.h = __float2bfloat16(f);
    return u.s;
}

// featb: [n][64] bf16, c in [48,64) zero, row NVOX all-zero.
// wtb:   per k, 384 16B chunks: chunk=(ks*2+nt)*64+lane, elem j =
//        B[c=ks*16+(lane>>5)*8+j][o=nt*32+(lane&31)]  (32x32x16 B-operand).
// pairs: per k' (k!=13), compacted int2{n, gi}.
// center: out[n] = bf16(feat[n]) @ bf16(W[13]) with plain stores.
__global__ void __launch_bounds__(256)
mega_prep(const float* __restrict__ feat, const float* __restrict__ wk,
          const int* __restrict__ idx, short* __restrict__ featb,
          short* __restrict__ wtb, int2* __restrict__ pairs,
          int* __restrict__ cnt, float* __restrict__ out)
{
    const int b = blockIdx.x;
    const int tid = threadIdx.x;

    if (b < R0_BLKS) {                       // ---- featb convert ----
        int t = b * 256 + tid;
        if (t < FEAT_THREADS) {
            int g = t >> 3, c8 = (t & 7) * 8;
            short8 p = (short8){0, 0, 0, 0, 0, 0, 0, 0};
            if (g < NVOX && c8 < INC) {
                const floatx4* src = (const floatx4*)(feat + g * INC + c8);
                floatx4 f0 = src[0], f1 = src[1];
                #pragma unroll
                for (int j = 0; j < 4; ++j) { p[j] = f2bf(f0[j]); p[4 + j] = f2bf(f1[j]); }
            }
            *(short8*)(featb + g * FEAT_ROW + c8) = p;
        }
        return;
    }
    if (b < R0_BLKS + R1_BLKS) {             // ---- wtb repack ----
        int t = (b - R0_BLKS) * 256 + tid;   // < 82944 exact
        int k = t / WTB_K, r = t % WTB_K;
        int chunk = r >> 3, j = r & 7;
        int f = chunk >> 6, lane = chunk & 63;
        int ks = f >> 1, nt = f & 1;
        int c = ks * 16 + (lane >> 5) * 8 + j;
        int o = nt * 32 + (lane & 31);
        wtb[t] = f2bf(wk[k * (INC_MAX * OUTC_MAX) + c * OUTC_MAX + o]);
        return;
    }
    if (b < R0_BLKS + R1_BLKS + R2_BLKS) {   // ---- compaction (k != 13) ----
        int t = (b - R0_BLKS - R1_BLKS) * 256 + tid;
        if (t < 26 * NVOX) {
            int kp = t / NVOX, n = t - kp * NVOX;
            int k = kp + (kp >= KCENTER);
            int gi = idx[k * NVOX + n];
            if (gi >= 0) {
                int pos = atomicAdd(&cnt[kp], 1);
                pairs[kp * NVOX + pos] = make_int2(n, gi);
            }
        }
        return;
    }
    // ---- center GEMM from raw inputs (independent of featb/wtb) ----
    {
        int cb = b - (R0_BLKS + R1_BLKS + R2_BLKS);
        const int lane = tid & 63, wave = tid >> 6;
        const int l32 = lane & 31, hi = lane >> 5;
        const int m0 = (cb * 4 + wave) * 32;
        if (m0 >= NVOX) return;
        const int n = m0 + l32;

        // A frags: bf16 of feat[n], lane holds k = 8*hi + j per ks
        short8 A[3];
        const float* fr = feat + n * INC;
        #pragma unroll
        for (int ks = 0; ks < 3; ++ks) {
            floatx4 u = *(const floatx4*)(fr + ks * 16 + hi * 8);
            floatx4 v = *(const floatx4*)(fr + ks * 16 + hi * 8 + 4);
            #pragma unroll
            for (int j = 0; j < 4; ++j) { A[ks][j] = f2bf(u[j]); A[ks][4 + j] = f2bf(v[j]); }
        }
        // B frags: W[13][c][o], lane holds (k=8hi+j, n=nt*32+l32)
        const float* w13 = wk + KCENTER * (INC_MAX * OUTC_MAX);
        short8 bfr[3][2];
        #pragma unroll
        for (int ks = 0; ks < 3; ++ks)
            #pragma unroll
            for (int nt = 0; nt < 2; ++nt)
                #pragma unroll
                for (int j = 0; j < 8; ++j)
                    bfr[ks][nt][j] = f2bf(w13[(ks * 16 + hi * 8 + j) * OUTC_MAX + nt * 32 + l32]);

        floatx16 a0, a1;
        #pragma unroll
        for (int r = 0; r < 16; ++r) { a0[r] = 0.f; a1[r] = 0.f; }
        #pragma unroll
        for (int ks = 0; ks < 3; ++ks) {
            a0 = __builtin_amdgcn_mfma_f32_32x32x16_bf16(A[ks], bfr[ks][0], a0, 0, 0, 0);
            a1 = __builtin_amdgcn_mfma_f32_32x32x16_bf16(A[ks], bfr[ks][1], a1, 0, 0, 0);
        }
        #pragma unroll
        for (int r = 0; r < 16; ++r) {
            int row = (r & 3) + 8 * (r >> 2) + 4 * hi;
            out[(m0 + row) * OUTC + l32]      = a0[r];
            out[(m0 + row) * OUTC + 32 + l32] = a1[r];
        }
    }
}

// 1 block: prefix over 26 counts -> tile descriptors {k|(nvalid<<8), pairbase}.
__global__ void __launch_bounds__(256)
build_desc(int* __restrict__ cnt, int2* __restrict__ desc)
{
    __shared__ int ofs[26];
    if (threadIdx.x == 0) {
        int tot = 0;
        for (int kp = 0; kp < 26; ++kp) { ofs[kp] = tot; tot += (cnt[kp] + 31) >> 5; }
        cnt[26] = tot;                        // ntiles
    }
    __syncthreads();
    for (int kp = 0; kp < 26; ++kp) {
        int c = cnt[kp], nt = (c + 31) >> 5, base = ofs[kp];
        int k = kp + (kp >= KCENTER);
        for (int i = threadIdx.x; i < nt; i += 256) {
            int nv = c - i * 32; if (nv > 32) nv = 32;
            desc[base + i] = make_int2(k | (nv << 8), kp * NVOX + i * 32);
        }
    }
}

// Persistent scatter-GEMM: one 32-pair tile per wave-slot iteration.
__global__ void __launch_bounds__(256, 4)
scatter_gemm(const short* __restrict__ featb, const short* __restrict__ wtb,
             const int2* __restrict__ pairs, const int2* __restrict__ desc,
             const int* __restrict__ cnt, float* __restrict__ out)
{
    const int lane = threadIdx.x & 63, wave = threadIdx.x >> 6;
    const int l32 = lane & 31, hi = lane >> 5;
    const int ntiles = cnt[26];
    const int nslots = gridDim.x * 4;

    for (int t = blockIdx.x * 4 + wave; t < ntiles; t += nslots) {
        int2 d = desc[t];
        int k = d.x & 255, nv = (d.x >> 8) & 255, base = d.y;

        int2 p = (l32 < nv) ? pairs[base + l32] : make_int2(-1, NVOX);

        const short* fp = featb + p.y * FEAT_ROW + hi * 8;
        short8 A0 = *(const short8*)(fp);
        short8 A1 = *(const short8*)(fp + 16);
        short8 A2 = *(const short8*)(fp + 32);

        const short* wb = wtb + k * WTB_K;
        short8 bfr[3][2];
        #pragma unroll
        for (int ks = 0; ks < 3; ++ks)
            #pragma unroll
            for (int nt = 0; nt < 2; ++nt)
                bfr[ks][nt] = *(const short8*)(wb + ((ks * 2 + nt) * 64 + lane) * 8);

        floatx16 a0, a1;
        #pragma unroll
        for (int r = 0; r < 16; ++r) { a0[r] = 0.f; a1[r] = 0.f; }
        a0 = __builtin_amdgcn_mfma_f32_32x32x16_bf16(A0, bfr[0][0], a0, 0, 0, 0);
        a1 = __builtin_amdgcn_mfma_f32_32x32x16_bf16(A0, bfr[0][1], a1, 0, 0, 0);
        a0 = __builtin_amdgcn_mfma_f32_32x32x16_bf16(A1, bfr[1][0], a0, 0, 0, 0);
        a1 = __builtin_amdgcn_mfma_f32_32x32x16_bf16(A1, bfr[1][1], a1, 0, 0, 0);
        a0 = __builtin_amdgcn_mfma_f32_32x32x16_bf16(A2, bfr[2][0], a0, 0, 0, 0);
        a1 = __builtin_amdgcn_mfma_f32_32x32x16_bf16(A2, bfr[2][1], a1, 0, 0, 0);

        #pragma unroll
        for (int r = 0; r < 16; ++r) {
            int row = (r & 3) + 8 * (r >> 2) + 4 * hi;
            int n = __shfl(p.x, row);         // lane 'row' holds slot 'row'
            if (n >= 0) {
                atomicAdd(&out[n * OUTC + l32],      a0[r]);
                atomicAdd(&out[n * OUTC + 32 + l32], a1[r]);
            }
        }
    }
}

// Safety fallback (only if workspace too small): plain fp32.
__global__ void __launch_bounds__(256)
spconv_fallback(const float* __restrict__ feat, const float* __restrict__ wk,
                const int* __restrict__ idx, float* __restrict__ out)
{
    int t = blockIdx.x * 256 + threadIdx.x;
    if (t >= NVOX * OUTC) return;
    int n = t >> 6, o = t & 63;
    float s = 0.f;
    for (int k = 0; k < KOFF; ++k) {
        int g = idx[k * NVOX + n];
        if (g >= 0) {
            const float* fr = feat + g * INC;
            const float* wr = wk + k * (INC_MAX * OUTC_MAX) + o;
            #pragma unroll 8
            for (int c = 0; c < INC; ++c) s += fr[c] * wr[c * OUTC_MAX];
        }
    }
    out[t] = s;
}

extern "C" void kernel_launch(void* const* d_in, const int* in_sizes, int n_in,
                              void* d_out, int out_size, void* d_ws, size_t ws_size,
                              hipStream_t stream) {
    const float* feat = (const float*)d_in[0];
    const float* wk   = (const float*)d_in[1];
    const int*   idx  = (const int*)d_in[2];
    float* out = (float*)d_out;

    if (ws_size >= WS_NEED) {
        char* ws = (char*)d_ws;
        short* featb = (short*)(ws + FEATB_OFF);
        short* wtb   = (short*)(ws + WTB_OFF);
        int2*  pairs = (int2*)(ws + PAIRS_OFF);
        int2*  desc  = (int2*)(ws + DESC_OFF);
        int*   cnt   = (int*)(ws + CNT_OFF);

        hipMemsetAsync(cnt, 0, CNT_BYTES, stream);
        mega_prep<<<MEGA_BLKS, 256, 0, stream>>>(feat, wk, idx, featb, wtb,
                                                 pairs, cnt, out);
        build_desc<<<1, 256, 0, stream>>>(cnt, desc);
        scatter_gemm<<<SCAT_BLKS, 256, 0, stream>>>(featb, wtb, pairs, desc,
                                                    cnt, out);
    } else {
        spconv_fallback<<<(NVOX * OUTC + 255) / 256, 256, 0, stream>>>(feat, wk, idx, out);
    }
}

// Round 8
// 234.426 us; speedup vs baseline: 6.2391x; 6.2391x over previous
//
#include <hip/hip_runtime.h>
#include <hip/hip_bf16.h>

// SparseDynamicConv3d: out[n,o] = sum_k sum_c feat[idx[k,n],c] * W[k,c,o]
// Round 8: r7 rulebook with the atomic-contention bug fixed.
//   - compaction: kp-uniform blocks, wave ballot + block LDS combine ->
//     ONE global atomicAdd per block (was: one per valid element, 2.6M ops
//     on 26 counters => 1.36 ms stall).
//   - build_desc: lane-parallel counts + shfl scan (was serial thread-0).
// MFMA layouts identical to validated r6/r7 (32x32x16 bf16, K=48 exact).

#define NVOX       100000
#define INC        48
#define INC_MAX    64
#define OUTC       64
#define OUTC_MAX   96
#define KOFF       27
#define KCENTER    13
#define FEAT_ROW   64                        // bf16 row padded to 128 B
#define WTB_K      3072                      // shorts per k (48x64 frag-packed)

// ---- workspace layout (bytes) ----
#define FEATB_OFF  0
#define FEATB_BYTES ((size_t)(NVOX + 1) * FEAT_ROW * 2)          // 12,800,128
#define WTB_OFF    (FEATB_OFF + FEATB_BYTES)
#define WTB_BYTES  ((size_t)KOFF * WTB_K * 2)                    // 165,888
#define PAIRS_OFF  (WTB_OFF + WTB_BYTES)
#define PAIRS_BYTES ((size_t)26 * NVOX * 8)                      // 20,800,000
#define DESC_OFF   (PAIRS_OFF + PAIRS_BYTES)
#define DESC_BYTES ((size_t)26 * 3125 * 8)                       // 650,000
#define CNT_OFF    (DESC_OFF + DESC_BYTES)
#define CNT_BYTES  128                                           // 26 cnt + ntiles
#define WS_NEED    (CNT_OFF + CNT_BYTES)

// ---- mega-kernel block ranges ----
#define FEAT_THREADS ((NVOX + 1) * 8)
#define R0_BLKS    ((FEAT_THREADS + 255) / 256)    // 3126 : featb convert
#define R1_BLKS    (KOFF * WTB_K / 256)            // 324  : wtb repack
#define NB_PER_KP  ((NVOX + 255) / 256)            // 391
#define R2_BLKS    (26 * NB_PER_KP)                // 10166: compaction
#define R3_BLKS    782                             // center GEMM (3125 waves)
#define MEGA_BLKS  (R0_BLKS + R1_BLKS + R2_BLKS + R3_BLKS)

#define SCAT_BLKS  1024

typedef __attribute__((ext_vector_type(8)))  short short8;
typedef __attribute__((ext_vector_type(4)))  float floatx4;
typedef __attribute__((ext_vector_type(16))) float floatx16;

__device__ __forceinline__ short f2bf(float f) {
    union { __hip_bfloat16 h; short s; } u;
    u.h = __float2bfloat16(f);
    return u.s;
}

// featb: [n][64] bf16, c in [48,64) zero, row NVOX all-zero.
// wtb:   per k, 384 16B chunks: chunk=(ks*2+nt)*64+lane, elem j =
//        B[c=ks*16+(lane>>5)*8+j][o=nt*32+(lane&31)]  (32x32x16 B-operand).
// pairs: per kp (k!=13), compacted int2{n, gi}.
// center: out[n] = bf16(feat[n]) @ bf16(W[13]) with plain stores.
__global__ void __launch_bounds__(256)
mega_prep(const float* __restrict__ feat, const float* __restrict__ wk,
          const int* __restrict__ idx, short* __restrict__ featb,
          short* __restrict__ wtb, int2* __restrict__ pairs,
          int* __restrict__ cnt, float* __restrict__ out)
{
    __shared__ int wcnt[4], wbase[4];
    const int b = blockIdx.x;
    const int tid = threadIdx.x;

    if (b < R0_BLKS) {                       // ---- featb convert ----
        int t = b * 256 + tid;
        if (t < FEAT_THREADS) {
            int g = t >> 3, c8 = (t & 7) * 8;
            short8 p = (short8){0, 0, 0, 0, 0, 0, 0, 0};
            if (g < NVOX && c8 < INC) {
                const floatx4* src = (const floatx4*)(feat + g * INC + c8);
                floatx4 f0 = src[0], f1 = src[1];
                #pragma unroll
                for (int j = 0; j < 4; ++j) { p[j] = f2bf(f0[j]); p[4 + j] = f2bf(f1[j]); }
            }
            *(short8*)(featb + g * FEAT_ROW + c8) = p;
        }
        return;
    }
    if (b < R0_BLKS + R1_BLKS) {             // ---- wtb repack ----
        int t = (b - R0_BLKS) * 256 + tid;   // < 82944 exact
        int k = t / WTB_K, r = t % WTB_K;
        int chunk = r >> 3, j = r & 7;
        int f = chunk >> 6, lane = chunk & 63;
        int ks = f >> 1, nt = f & 1;
        int c = ks * 16 + (lane >> 5) * 8 + j;
        int o = nt * 32 + (lane & 31);
        wtb[t] = f2bf(wk[k * (INC_MAX * OUTC_MAX) + c * OUTC_MAX + o]);
        return;
    }
    if (b < R0_BLKS + R1_BLKS + R2_BLKS) {   // ---- compaction (k != 13) ----
        int b2 = b - R0_BLKS - R1_BLKS;
        int kp = b2 / NB_PER_KP, nb = b2 - kp * NB_PER_KP;
        int n  = nb * 256 + tid;
        int k  = kp + (kp >= KCENTER);
        int gi = (n < NVOX) ? idx[k * NVOX + n] : -1;
        bool valid = gi >= 0;

        unsigned long long mask = __ballot(valid);
        int wv = tid >> 6, lane = tid & 63;
        if (lane == 0) wcnt[wv] = __popcll(mask);
        __syncthreads();
        if (tid == 0) {
            int t0 = wcnt[0], t1 = wcnt[1], t2 = wcnt[2], t3 = wcnt[3];
            int bb = atomicAdd(&cnt[kp], t0 + t1 + t2 + t3);
            wbase[0] = bb; wbase[1] = bb + t0;
            wbase[2] = bb + t0 + t1; wbase[3] = bb + t0 + t1 + t2;
        }
        __syncthreads();
        if (valid) {
            int rank = __popcll(mask & ((1ull << lane) - 1ull));
            pairs[kp * NVOX + wbase[wv] + rank] = make_int2(n, gi);
        }
        return;
    }
    // ---- center GEMM from raw inputs ----
    {
        int cb = b - (R0_BLKS + R1_BLKS + R2_BLKS);
        const int lane = tid & 63, wave = tid >> 6;
        const int l32 = lane & 31, hi = lane >> 5;
        const int m0 = (cb * 4 + wave) * 32;
        if (m0 >= NVOX) return;
        const int n = m0 + l32;

        short8 A[3];
        const float* fr = feat + n * INC;
        #pragma unroll
        for (int ks = 0; ks < 3; ++ks) {
            floatx4 u = *(const floatx4*)(fr + ks * 16 + hi * 8);
            floatx4 v = *(const floatx4*)(fr + ks * 16 + hi * 8 + 4);
            #pragma unroll
            for (int j = 0; j < 4; ++j) { A[ks][j] = f2bf(u[j]); A[ks][4 + j] = f2bf(v[j]); }
        }
        const float* w13 = wk + KCENTER * (INC_MAX * OUTC_MAX);
        short8 bfr[3][2];
        #pragma unroll
        for (int ks = 0; ks < 3; ++ks)
            #pragma unroll
            for (int nt = 0; nt < 2; ++nt)
                #pragma unroll
                for (int j = 0; j < 8; ++j)
                    bfr[ks][nt][j] = f2bf(w13[(ks * 16 + hi * 8 + j) * OUTC_MAX + nt * 32 + l32]);

        floatx16 a0, a1;
        #pragma unroll
        for (int r = 0; r < 16; ++r) { a0[r] = 0.f; a1[r] = 0.f; }
        #pragma unroll
        for (int ks = 0; ks < 3; ++ks) {
            a0 = __builtin_amdgcn_mfma_f32_32x32x16_bf16(A[ks], bfr[ks][0], a0, 0, 0, 0);
            a1 = __builtin_amdgcn_mfma_f32_32x32x16_bf16(A[ks], bfr[ks][1], a1, 0, 0, 0);
        }
        #pragma unroll
        for (int r = 0; r < 16; ++r) {
            int row = (r & 3) + 8 * (r >> 2) + 4 * hi;
            out[(m0 + row) * OUTC + l32]      = a0[r];
            out[(m0 + row) * OUTC + 32 + l32] = a1[r];
        }
    }
}

// 1 block: lane-parallel prefix over 26 tile counts -> descriptors.
__global__ void __launch_bounds__(256)
build_desc(int* __restrict__ cnt, int2* __restrict__ desc)
{
    __shared__ int ofs[26], cs[26];
    const int tid = threadIdx.x;
    if (tid < 32) {
        int c = (tid < 26) ? cnt[tid] : 0;
        int t = (c + 31) >> 5;
        int s = t;
        #pragma unroll
        for (int d = 1; d < 32; d <<= 1) {
            int v = __shfl_up(s, d, 32);
            if (tid >= d) s += v;
        }
        if (tid < 26) { ofs[tid] = s - t; cs[tid] = c; }
        if (tid == 25) cnt[26] = s;      // ntiles
    }
    __syncthreads();
    for (int kp = 0; kp < 26; ++kp) {
        int c = cs[kp], nt = (c + 31) >> 5, base = ofs[kp];
        int k = kp + (kp >= KCENTER);
        for (int i = tid; i < nt; i += 256) {
            int nv = c - i * 32; if (nv > 32) nv = 32;
            desc[base + i] = make_int2(k | (nv << 8), kp * NVOX + i * 32);
        }
    }
}

// Persistent scatter-GEMM: one 32-pair tile per wave-slot iteration.
__global__ void __launch_bounds__(256, 4)
scatter_gemm(const short* __restrict__ featb, const short* __restrict__ wtb,
             const int2* __restrict__ pairs, const int2* __restrict__ desc,
             const int* __restrict__ cnt, float* __restrict__ out)
{
    const int lane = threadIdx.x & 63, wave = threadIdx.x >> 6;
    const int l32 = lane & 31, hi = lane >> 5;
    const int ntiles = cnt[26];
    const int nslots = gridDim.x * 4;

    for (int t = blockIdx.x * 4 + wave; t < ntiles; t += nslots) {
        int2 d = desc[t];
        int k = d.x & 255, nv = (d.x >> 8) & 255, base = d.y;

        int2 p = (l32 < nv) ? pairs[base + l32] : make_int2(-1, NVOX);

        const short* fp = featb + p.y * FEAT_ROW + hi * 8;
        short8 A0 = *(const short8*)(fp);
        short8 A1 = *(const short8*)(fp + 16);
        short8 A2 = *(const short8*)(fp + 32);

        const short* wb = wtb + k * WTB_K;
        short8 bfr[3][2];
        #pragma unroll
        for (int ks = 0; ks < 3; ++ks)
            #pragma unroll
            for (int nt = 0; nt < 2; ++nt)
                bfr[ks][nt] = *(const short8*)(wb + ((ks * 2 + nt) * 64 + lane) * 8);

        floatx16 a0, a1;
        #pragma unroll
        for (int r = 0; r < 16; ++r) { a0[r] = 0.f; a1[r] = 0.f; }
        a0 = __builtin_amdgcn_mfma_f32_32x32x16_bf16(A0, bfr[0][0], a0, 0, 0, 0);
        a1 = __builtin_amdgcn_mfma_f32_32x32x16_bf16(A0, bfr[0][1], a1, 0, 0, 0);
        a0 = __builtin_amdgcn_mfma_f32_32x32x16_bf16(A1, bfr[1][0], a0, 0, 0, 0);
        a1 = __builtin_amdgcn_mfma_f32_32x32x16_bf16(A1, bfr[1][1], a1, 0, 0, 0);
        a0 = __builtin_amdgcn_mfma_f32_32x32x16_bf16(A2, bfr[2][0], a0, 0, 0, 0);
        a1 = __builtin_amdgcn_mfma_f32_32x32x16_bf16(A2, bfr[2][1], a1, 0, 0, 0);

        #pragma unroll
        for (int r = 0; r < 16; ++r) {
            int row = (r & 3) + 8 * (r >> 2) + 4 * hi;
            int n = __shfl(p.x, row);
            if (n >= 0) {
                atomicAdd(&out[n * OUTC + l32],      a0[r]);
                atomicAdd(&out[n * OUTC + 32 + l32], a1[r]);
            }
        }
    }
}

// Safety fallback (only if workspace too small): plain fp32.
__global__ void __launch_bounds__(256)
spconv_fallback(const float* __restrict__ feat, const float* __restrict__ wk,
                const int* __restrict__ idx, float* __restrict__ out)
{
    int t = blockIdx.x * 256 + threadIdx.x;
    if (t >= NVOX * OUTC) return;
    int n = t >> 6, o = t & 63;
    float s = 0.f;
    for (int k = 0; k < KOFF; ++k) {
        int g = idx[k * NVOX + n];
        if (g >= 0) {
            const float* fr = feat + g * INC;
            const float* wr = wk + k * (INC_MAX * OUTC_MAX) + o;
            #pragma unroll 8
            for (int c = 0; c < INC; ++c) s += fr[c] * wr[c * OUTC_MAX];
        }
    }
    out[t] = s;
}

extern "C" void kernel_launch(void* const* d_in, const int* in_sizes, int n_in,
                              void* d_out, int out_size, void* d_ws, size_t ws_size,
                              hipStream_t stream) {
    const float* feat = (const float*)d_in[0];
    const float* wk   = (const float*)d_in[1];
    const int*   idx  = (const int*)d_in[2];
    float* out = (float*)d_out;

    if (ws_size >= WS_NEED) {
        char* ws = (char*)d_ws;
        short* featb = (short*)(ws + FEATB_OFF);
        short* wtb   = (short*)(ws + WTB_OFF);
        int2*  pairs = (int2*)(ws + PAIRS_OFF);
        int2*  desc  = (int2*)(ws + DESC_OFF);
        int*   cnt   = (int*)(ws + CNT_OFF);

        hipMemsetAsync(cnt, 0, CNT_BYTES, stream);
        mega_prep<<<MEGA_BLKS, 256, 0, stream>>>(feat, wk, idx, featb, wtb,
                                                 pairs, cnt, out);
        build_desc<<<1, 256, 0, stream>>>(cnt, desc);
        scatter_gemm<<<SCAT_BLKS, 256, 0, stream>>>(featb, wtb, pairs, desc,
                                                    cnt, out);
    } else {
        spconv_fallback<<<(NVOX * OUTC + 255) / 256, 256, 0, stream>>>(feat, wk, idx, out);
    }
}

// Round 9
// 145.335 us; speedup vs baseline: 10.0637x; 1.6130x over previous
//
#include <hip/hip_runtime.h>
#include <hip/hip_bf16.h>

// SparseDynamicConv3d: out[n,o] = sum_k sum_c feat[idx[k,n],c] * W[k,c,o]
// Round 9: r8 with the atomic chain length fixed by SEGMENTED compaction.
//   - 416 counters (26 kp x 16 segments): max 25 serialized atomics/counter
//     (was 391 x ~700cyc = 114us -- the whole r8 regression).
//   - pairs stored in fixed 6400-pair segment regions; tile descriptors are
//     DERIVED arithmetically in scatter_gemm from the 416 counts (LDS-cached)
//     -- build_desc kernel eliminated.
// MFMA layouts identical to validated r6/r7/r8 (32x32x16 bf16, K=48 exact).

#define NVOX       100000
#define INC        48
#define INC_MAX    64
#define OUTC       64
#define OUTC_MAX   96
#define KOFF       27
#define KCENTER    13
#define FEAT_ROW   64                        // bf16 row padded to 128 B
#define WTB_K      3072                      // shorts per k (48x64 frag-packed)

#define NSEG       16                        // segments per kp
#define SEG_CAP    6400                      // max pairs/segment (25 blks x 256)
#define SEG_TILES  (SEG_CAP / 32)            // 200 tile slots per segment
#define NSEGTOT    (26 * NSEG)               // 416
#define NSLOTS     (NSEGTOT * SEG_TILES)     // 83,200 derived tile slots

// ---- workspace layout (bytes) ----
#define FEATB_OFF  0
#define FEATB_BYTES ((size_t)(NVOX + 1) * FEAT_ROW * 2)          // 12,800,128
#define WTB_OFF    (FEATB_OFF + FEATB_BYTES)
#define WTB_BYTES  ((size_t)KOFF * WTB_K * 2)                    // 165,888
#define PAIRS_OFF  (WTB_OFF + WTB_BYTES)
#define PAIRS_BYTES ((size_t)NSEGTOT * SEG_CAP * 8)              // 21,299,200
#define CNT_OFF    (PAIRS_OFF + PAIRS_BYTES)
#define CNT_BYTES  (NSEGTOT * 4)                                 // 1664
#define WS_NEED    (CNT_OFF + CNT_BYTES)

// ---- mega-kernel block ranges ----
#define FEAT_THREADS ((NVOX + 1) * 8)
#define R0_BLKS    ((FEAT_THREADS + 255) / 256)    // 3126 : featb convert
#define R1_BLKS    (KOFF * WTB_K / 256)            // 324  : wtb repack
#define NB_PER_KP  ((NVOX + 255) / 256)            // 391
#define R2_BLKS    (26 * NB_PER_KP)                // 10166: compaction
#define R3_BLKS    782                             // center GEMM (3125 waves)
#define MEGA_BLKS  (R0_BLKS + R1_BLKS + R2_BLKS + R3_BLKS)

#define SCAT_BLKS  1024

typedef __attribute__((ext_vector_type(8)))  short short8;
typedef __attribute__((ext_vector_type(4)))  float floatx4;
typedef __attribute__((ext_vector_type(16))) float floatx16;

__device__ __forceinline__ short f2bf(float f) {
    union { __hip_bfloat16 h; short s; } u;
    u.h = __float2bfloat16(f);
    return u.s;
}

// featb: [n][64] bf16, c in [48,64) zero, row NVOX all-zero.
// wtb:   per k, 384 16B chunks: chunk=(ks*2+nt)*64+lane, elem j =
//        B[c=ks*16+(lane>>5)*8+j][o=nt*32+(lane&31)]  (32x32x16 B-operand).
// pairs: segment sg = kp*16 + (nb&15), region [sg*SEG_CAP, +cnt[sg]).
// center: out[n] = bf16(feat[n]) @ bf16(W[13]) with plain stores (idx[13]=n).
__global__ void __launch_bounds__(256)
mega_prep(const float* __restrict__ feat, const float* __restrict__ wk,
          const int* __restrict__ idx, short* __restrict__ featb,
          short* __restrict__ wtb, int2* __restrict__ pairs,
          int* __restrict__ cnt, float* __restrict__ out)
{
    __shared__ int wcnt[4], wbase[4];
    const int b = blockIdx.x;
    const int tid = threadIdx.x;

    if (b < R0_BLKS) {                       // ---- featb convert ----
        int t = b * 256 + tid;
        if (t < FEAT_THREADS) {
            int g = t >> 3, c8 = (t & 7) * 8;
            short8 p = (short8){0, 0, 0, 0, 0, 0, 0, 0};
            if (g < NVOX && c8 < INC) {
                const floatx4* src = (const floatx4*)(feat + g * INC + c8);
                floatx4 f0 = src[0], f1 = src[1];
                #pragma unroll
                for (int j = 0; j < 4; ++j) { p[j] = f2bf(f0[j]); p[4 + j] = f2bf(f1[j]); }
            }
            *(short8*)(featb + g * FEAT_ROW + c8) = p;
        }
        return;
    }
    if (b < R0_BLKS + R1_BLKS) {             // ---- wtb repack ----
        int t = (b - R0_BLKS) * 256 + tid;   // < 82944 exact
        int k = t / WTB_K, r = t % WTB_K;
        int chunk = r >> 3, j = r & 7;
        int f = chunk >> 6, lane = chunk & 63;
        int ks = f >> 1, nt = f & 1;
        int c = ks * 16 + (lane >> 5) * 8 + j;
        int o = nt * 32 + (lane & 31);
        wtb[t] = f2bf(wk[k * (INC_MAX * OUTC_MAX) + c * OUTC_MAX + o]);
        return;
    }
    if (b < R0_BLKS + R1_BLKS + R2_BLKS) {   // ---- segmented compaction ----
        int b2 = b - R0_BLKS - R1_BLKS;
        int kp = b2 / NB_PER_KP, nb = b2 - kp * NB_PER_KP;
        int sg = kp * NSEG + (nb & (NSEG - 1));
        int n  = nb * 256 + tid;
        int k  = kp + (kp >= KCENTER);
        int gi = (n < NVOX) ? idx[k * NVOX + n] : -1;
        bool valid = gi >= 0;

        unsigned long long mask = __ballot(valid);
        int wv = tid >> 6, lane = tid & 63;
        if (lane == 0) wcnt[wv] = __popcll(mask);
        __syncthreads();
        if (tid == 0) {
            int t0 = wcnt[0], t1 = wcnt[1], t2 = wcnt[2], t3 = wcnt[3];
            int bb = atomicAdd(&cnt[sg], t0 + t1 + t2 + t3);
            wbase[0] = bb; wbase[1] = bb + t0;
            wbase[2] = bb + t0 + t1; wbase[3] = bb + t0 + t1 + t2;
        }
        __syncthreads();
        if (valid) {
            int rank = __popcll(mask & ((1ull << lane) - 1ull));
            pairs[sg * SEG_CAP + wbase[wv] + rank] = make_int2(n, gi);
        }
        return;
    }
    // ---- center GEMM from raw inputs ----
    {
        int cb = b - (R0_BLKS + R1_BLKS + R2_BLKS);
        const int lane = tid & 63, wave = tid >> 6;
        const int l32 = lane & 31, hi = lane >> 5;
        const int m0 = (cb * 4 + wave) * 32;
        if (m0 >= NVOX) return;
        const int n = m0 + l32;

        short8 A[3];
        const float* fr = feat + n * INC;
        #pragma unroll
        for (int ks = 0; ks < 3; ++ks) {
            floatx4 u = *(const floatx4*)(fr + ks * 16 + hi * 8);
            floatx4 v = *(const floatx4*)(fr + ks * 16 + hi * 8 + 4);
            #pragma unroll
            for (int j = 0; j < 4; ++j) { A[ks][j] = f2bf(u[j]); A[ks][4 + j] = f2bf(v[j]); }
        }
        const float* w13 = wk + KCENTER * (INC_MAX * OUTC_MAX);
        short8 bfr[3][2];
        #pragma unroll
        for (int ks = 0; ks < 3; ++ks)
            #pragma unroll
            for (int nt = 0; nt < 2; ++nt)
                #pragma unroll
                for (int j = 0; j < 8; ++j)
                    bfr[ks][nt][j] = f2bf(w13[(ks * 16 + hi * 8 + j) * OUTC_MAX + nt * 32 + l32]);

        floatx16 a0, a1;
        #pragma unroll
        for (int r = 0; r < 16; ++r) { a0[r] = 0.f; a1[r] = 0.f; }
        #pragma unroll
        for (int ks = 0; ks < 3; ++ks) {
            a0 = __builtin_amdgcn_mfma_f32_32x32x16_bf16(A[ks], bfr[ks][0], a0, 0, 0, 0);
            a1 = __builtin_amdgcn_mfma_f32_32x32x16_bf16(A[ks], bfr[ks][1], a1, 0, 0, 0);
        }
        #pragma unroll
        for (int r = 0; r < 16; ++r) {
            int row = (r & 3) + 8 * (r >> 2) + 4 * hi;
            out[(m0 + row) * OUTC + l32]      = a0[r];
            out[(m0 + row) * OUTC + 32 + l32] = a1[r];
        }
    }
}

// Persistent scatter-GEMM over derived tile slots; counts cached in LDS.
__global__ void __launch_bounds__(256, 4)
scatter_gemm(const short* __restrict__ featb, const short* __restrict__ wtb,
             const int2* __restrict__ pairs, const int* __restrict__ cnt,
             float* __restrict__ out)
{
    __shared__ int scnt[NSEGTOT];
    const int tid = threadIdx.x;
    for (int i = tid; i < NSEGTOT; i += 256) scnt[i] = cnt[i];
    __syncthreads();

    const int lane = tid & 63, wave = tid >> 6;
    const int l32 = lane & 31, hi = lane >> 5;
    const int nslots = gridDim.x * 4;

    for (int t = blockIdx.x * 4 + wave; t < NSLOTS; t += nslots) {
        int sg = t / SEG_TILES;
        int i  = t - sg * SEG_TILES;
        int c  = scnt[sg];
        if (i * 32 >= c) continue;
        int nv = c - i * 32; if (nv > 32) nv = 32;
        int kp = sg >> 4;
        int k  = kp + (kp >= KCENTER);
        int base = sg * SEG_CAP + i * 32;

        int2 p = (l32 < nv) ? pairs[base + l32] : make_int2(-1, NVOX);

        const short* fp = featb + p.y * FEAT_ROW + hi * 8;
        short8 A0 = *(const short8*)(fp);
        short8 A1 = *(const short8*)(fp + 16);
        short8 A2 = *(const short8*)(fp + 32);

        const short* wb = wtb + k * WTB_K;
        short8 bfr[3][2];
        #pragma unroll
        for (int ks = 0; ks < 3; ++ks)
            #pragma unroll
            for (int nt = 0; nt < 2; ++nt)
                bfr[ks][nt] = *(const short8*)(wb + ((ks * 2 + nt) * 64 + lane) * 8);

        floatx16 a0, a1;
        #pragma unroll
        for (int r = 0; r < 16; ++r) { a0[r] = 0.f; a1[r] = 0.f; }
        a0 = __builtin_amdgcn_mfma_f32_32x32x16_bf16(A0, bfr[0][0], a0, 0, 0, 0);
        a1 = __builtin_amdgcn_mfma_f32_32x32x16_bf16(A0, bfr[0][1], a1, 0, 0, 0);
        a0 = __builtin_amdgcn_mfma_f32_32x32x16_bf16(A1, bfr[1][0], a0, 0, 0, 0);
        a1 = __builtin_amdgcn_mfma_f32_32x32x16_bf16(A1, bfr[1][1], a1, 0, 0, 0);
        a0 = __builtin_amdgcn_mfma_f32_32x32x16_bf16(A2, bfr[2][0], a0, 0, 0, 0);
        a1 = __builtin_amdgcn_mfma_f32_32x32x16_bf16(A2, bfr[2][1], a1, 0, 0, 0);

        #pragma unroll
        for (int r = 0; r < 16; ++r) {
            int row = (r & 3) + 8 * (r >> 2) + 4 * hi;
            int n = __shfl(p.x, row);
            if (n >= 0) {
                atomicAdd(&out[n * OUTC + l32],      a0[r]);
                atomicAdd(&out[n * OUTC + 32 + l32], a1[r]);
            }
        }
    }
}

// Safety fallback (only if workspace too small): plain fp32.
__global__ void __launch_bounds__(256)
spconv_fallback(const float* __restrict__ feat, const float* __restrict__ wk,
                const int* __restrict__ idx, float* __restrict__ out)
{
    int t = blockIdx.x * 256 + threadIdx.x;
    if (t >= NVOX * OUTC) return;
    int n = t >> 6, o = t & 63;
    float s = 0.f;
    for (int k = 0; k < KOFF; ++k) {
        int g = idx[k * NVOX + n];
        if (g >= 0) {
            const float* fr = feat + g * INC;
            const float* wr = wk + k * (INC_MAX * OUTC_MAX) + o;
            #pragma unroll 8
            for (int c = 0; c < INC; ++c) s += fr[c] * wr[c * OUTC_MAX];
        }
    }
    out[t] = s;
}

extern "C" void kernel_launch(void* const* d_in, const int* in_sizes, int n_in,
                              void* d_out, int out_size, void* d_ws, size_t ws_size,
                              hipStream_t stream) {
    const float* feat = (const float*)d_in[0];
    const float* wk   = (const float*)d_in[1];
    const int*   idx  = (const int*)d_in[2];
    float* out = (float*)d_out;

    if (ws_size >= WS_NEED) {
        char* ws = (char*)d_ws;
        short* featb = (short*)(ws + FEATB_OFF);
        short* wtb   = (short*)(ws + WTB_OFF);
        int2*  pairs = (int2*)(ws + PAIRS_OFF);
        int*   cnt   = (int*)(ws + CNT_OFF);

        hipMemsetAsync(cnt, 0, CNT_BYTES, stream);
        mega_prep<<<MEGA_BLKS, 256, 0, stream>>>(feat, wk, idx, featb, wtb,
                                                 pairs, cnt, out);
        scatter_gemm<<<SCAT_BLKS, 256, 0, stream>>>(featb, wtb, pairs, cnt, out);
    } else {
        spconv_fallback<<<(NVOX * OUTC + 255) / 256, 256, 0, stream>>>(feat, wk, idx, out);
    }
}

// Round 10
// 109.608 us; speedup vs baseline: 13.3439x; 1.3259x over previous
//
#include <hip/hip_runtime.h>
#include <hip/hip_bf16.h>

// SparseDynamicConv3d: out[n,o] = sum_k sum_c feat[idx[k,n],c] * W[k,c,o]
// Round 10: back to the validated r6 dense-k structure; main reworked to
// M=64 rows/wave (2-wave blocks, grid 782): the 6 B-frag ds_read_b128 per k
// now feed 12 MFMA instead of 6, halving LDS-pipe cycles per FLOP (the r6
// binding resource). launch_bounds(128,2) so the deeper rings fit in VGPRs.
// prep/wtb layouts byte-identical to r6 (validated, 0 bank conflicts).

#define NVOX       100000
#define INC        48
#define INC_MAX    64
#define OUTC       64
#define OUTC_MAX   96
#define KOFF       27
#define FEAT_ROW   64                        // bf16 row padded to 128 B
#define FEATB_ELEMS ((NVOX + 1) * FEAT_ROW)  // +1 zero row for idx<0
#define WTB_K      3072                      // shorts per k: 48x64 frag-packed
#define WTB_ELEMS  (KOFF * WTB_K)            // 82944
#define WS_NEED    ((size_t)(FEATB_ELEMS + WTB_ELEMS) * 2)
#define FEAT_THREADS ((NVOX + 1) * 8)        // 800008
#define FEAT_PREP_BLKS ((FEAT_THREADS + 255) / 256)   // 3126
#define WTB_PREP_BLKS  (WTB_ELEMS / 256)     // 324 exact
#define MAIN_BLOCKS 782                      // 782 x 128 rows >= 100000

typedef __attribute__((ext_vector_type(8)))  short short8;
typedef __attribute__((ext_vector_type(4)))  float floatx4;
typedef __attribute__((ext_vector_type(16))) float floatx16;

__device__ __forceinline__ short f2bf(float f) {
    union { __hip_bfloat16 h; short s; } u;
    u.h = __float2bfloat16(f);
    return u.s;
}

// featb: [n][64] bf16, c in [48,64) zero, row NVOX all-zero (idx<0 target).
// wtb:   per k, 384 16B chunks: chunk=(ks*2+nt)*64+lane, elem j =
//        B[c=ks*16+(lane>>5)*8+j][o=nt*32+(lane&31)]  (32x32x16 B-operand).
__global__ void __launch_bounds__(256)
prep_cvt(const float* __restrict__ feat, const float* __restrict__ wk,
         short* __restrict__ featb, short* __restrict__ wtb)
{
    int b = blockIdx.x;
    if (b < FEAT_PREP_BLKS) {
        int t = b * 256 + threadIdx.x;
        if (t < FEAT_THREADS) {
            int g = t >> 3, c8 = (t & 7) * 8;
            short8 p = (short8){0, 0, 0, 0, 0, 0, 0, 0};
            if (g < NVOX && c8 < INC) {
                const floatx4* src = (const floatx4*)(feat + g * INC + c8);
                floatx4 f0 = src[0], f1 = src[1];
                #pragma unroll
                for (int j = 0; j < 4; ++j) { p[j] = f2bf(f0[j]); p[4 + j] = f2bf(f1[j]); }
            }
            *(short8*)(featb + g * FEAT_ROW + c8) = p;
        }
    } else {
        int t = (b - FEAT_PREP_BLKS) * 256 + threadIdx.x;   // < 82944 exact
        int k = t / WTB_K, r = t % WTB_K;
        int chunk = r >> 3, j = r & 7;
        int f = chunk >> 6, lane = chunk & 63;
        int ks = f >> 1, nt = f & 1;
        int c = ks * 16 + (lane >> 5) * 8 + j;      // 0..47, no pad
        int o = nt * 32 + (lane & 31);
        wtb[t] = f2bf(wk[k * (INC_MAX * OUTC_MAX) + c * OUTC_MAX + o]);
    }
}

__global__ void __launch_bounds__(128, 2)
spconv_main(const short* __restrict__ featb, const short* __restrict__ wtb,
            const int* __restrict__ idx, float* __restrict__ out)
{
    __shared__ short Bs[4][WTB_K];   // 4 x 6KB single-k B buffers

    const int tid  = threadIdx.x;    // 0..127
    const int lane = tid & 63;
    const int wave = tid >> 6;       // 0..1
    const int l32  = lane & 31;
    const int hi   = lane >> 5;      // which 8-channel half of each 16-ch k-step

    // XCD-contiguous swizzle (bijective for bid<776, identity tail)
    int bid = blockIdx.x;
    int sb  = (bid < 776) ? ((bid & 7) * 97 + (bid >> 3)) : bid;

    const int m0 = sb * 128 + wave * 64;       // this wave's 64-row base
    const int ra = m0 + l32;                   // lane row, low half
    const int rb = m0 + 32 + l32;              // lane row, high half
    const int rra = (ra < NVOX) ? ra : 0;      // clamped idx addresses
    const int rrb = (rb < NVOX) ? rb : 0;

    floatx16 acc[2][2];              // [mh][nt]
    #pragma unroll
    for (int i = 0; i < 2; ++i)
        #pragma unroll
        for (int j = 0; j < 2; ++j)
            #pragma unroll
            for (int r = 0; r < 16; ++r) acc[i][j][r] = 0.f;

    short8 A[2][2][3];   // [k&1][mh][ks] A-frag ring
    short8 bst[4][3];    // [k&3][chunk] B-stage ring (3 b128/thread/k)
    int    row0[4], row1[4];   // gathered rows (idx<0 -> NVOX zero row)

    auto ldrow = [&](int k) {
        int t0 = idx[k * NVOX + rra];
        int t1 = idx[k * NVOX + rrb];
        row0[k & 3] = (t0 < 0) ? NVOX : t0;
        row1[k & 3] = (t1 < 0) ? NVOX : t1;
    };
    auto aload = [&](int k) {
        const short* p0 = featb + row0[k & 3] * FEAT_ROW + hi * 8;
        const short* p1 = featb + row1[k & 3] * FEAT_ROW + hi * 8;
        #pragma unroll
        for (int ks = 0; ks < 3; ++ks) {
            A[k & 1][0][ks] = *(const short8*)(p0 + ks * 16);
            A[k & 1][1][ks] = *(const short8*)(p1 + ks * 16);
        }
    };
    auto bload = [&](int k) {
        #pragma unroll
        for (int c = 0; c < 3; ++c)
            bst[k & 3][c] = *(const short8*)(wtb + k * WTB_K + (c * 128 + tid) * 8);
    };
    auto commit = [&](int k) {
        #pragma unroll
        for (int c = 0; c < 3; ++c)
            *(short8*)&Bs[k & 3][(c * 128 + tid) * 8] = bst[k & 3][c];
    };
    auto compute = [&](int k) {
        #pragma unroll
        for (int ks = 0; ks < 3; ++ks) {
            short8 b0 = *(const short8*)&Bs[k & 3][((ks * 2 + 0) * 64 + lane) * 8];
            short8 b1 = *(const short8*)&Bs[k & 3][((ks * 2 + 1) * 64 + lane) * 8];
            acc[0][0] = __builtin_amdgcn_mfma_f32_32x32x16_bf16(A[k & 1][0][ks], b0, acc[0][0], 0, 0, 0);
            acc[0][1] = __builtin_amdgcn_mfma_f32_32x32x16_bf16(A[k & 1][0][ks], b1, acc[0][1], 0, 0, 0);
            acc[1][0] = __builtin_amdgcn_mfma_f32_32x32x16_bf16(A[k & 1][1][ks], b0, acc[1][0], 0, 0, 0);
            acc[1][1] = __builtin_amdgcn_mfma_f32_32x32x16_bf16(A[k & 1][1][ks], b1, acc[1][1], 0, 0, 0);
        }
    };

    // ---- prologue ----
    ldrow(0); ldrow(1); ldrow(2); ldrow(3);
    bload(0); bload(1);
    aload(0); aload(1);

    #pragma unroll
    for (int j = 0; j < 14; ++j) {
        const int kk = 2 * j;

        commit(kk);
        if (kk + 1 < KOFF) commit(kk + 1);
        __syncthreads();

        // stage next pair's B into regs; idx two pairs ahead
        if (kk + 2 < KOFF) bload(kk + 2);
        if (kk + 3 < KOFF) bload(kk + 3);
        if (kk + 4 < KOFF) ldrow(kk + 4);
        if (kk + 5 < KOFF) ldrow(kk + 5);

        compute(kk);
        if (kk + 2 < KOFF) aload(kk + 2);     // refills A[kk&1] after use
        if (kk + 1 < KOFF) {
            compute(kk + 1);
            if (kk + 3 < KOFF) aload(kk + 3);
        }
    }

    // ---- epilogue: D col = nt*32+l32, row = (r&3) + 8*(r>>2) + 4*hi ----
    #pragma unroll
    for (int mh = 0; mh < 2; ++mh) {
        #pragma unroll
        for (int r = 0; r < 16; ++r) {
            int g = m0 + mh * 32 + (r & 3) + 8 * (r >> 2) + 4 * hi;
            if (g < NVOX) {
                out[g * OUTC + l32]      = acc[mh][0][r];
                out[g * OUTC + 32 + l32] = acc[mh][1][r];
            }
        }
    }
}

// Safety fallback (only if workspace too small): plain fp32.
__global__ void __launch_bounds__(256)
spconv_fallback(const float* __restrict__ feat, const float* __restrict__ wk,
                const int* __restrict__ idx, float* __restrict__ out)
{
    int t = blockIdx.x * 256 + threadIdx.x;
    if (t >= NVOX * OUTC) return;
    int n = t >> 6, o = t & 63;
    float s = 0.f;
    for (int k = 0; k < KOFF; ++k) {
        int g = idx[k * NVOX + n];
        if (g >= 0) {
            const float* fr = feat + g * INC;
            const float* wr = wk + k * (INC_MAX * OUTC_MAX) + o;
            #pragma unroll 8
            for (int c = 0; c < INC; ++c) s += fr[c] * wr[c * OUTC_MAX];
        }
    }
    out[t] = s;
}

extern "C" void kernel_launch(void* const* d_in, const int* in_sizes, int n_in,
                              void* d_out, int out_size, void* d_ws, size_t ws_size,
                              hipStream_t stream) {
    const float* feat = (const float*)d_in[0];
    const float* wk   = (const float*)d_in[1];
    const int*   idx  = (const int*)d_in[2];
    float* out = (float*)d_out;

    if (ws_size >= WS_NEED) {
        short* featb = (short*)d_ws;
        short* wtb   = featb + FEATB_ELEMS;
        prep_cvt<<<FEAT_PREP_BLKS + WTB_PREP_BLKS, 256, 0, stream>>>(feat, wk, featb, wtb);
        spconv_main<<<MAIN_BLOCKS, 128, 0, stream>>>(featb, wtb, idx, out);
    } else {
        spconv_fallback<<<(NVOX * OUTC + 255) / 256, 256, 0, stream>>>(feat, wk, idx, out);
    }
}